// Round 10
// baseline (226.000 us; speedup 1.0000x reference)
//
#include <hip/hip_runtime.h>

// Attention block: B=16, C=512, H=W=32 (N=1024), GROUPS=8, EPS=1e-5
// All GEMMs NT-form bf16 MFMA, global_load_lds width-16 staging.
//
// R16 = R15 + 128x64 tiles for scores/pu (the two low-supply GEMMs):
//   Budget analysis (R15): fill tax ~41us (harness, untouchable); qku
//   41.5us @621 TF (5-6 resident) vs scores 41.6 @414 TF (4 resident),
//   pu ~38 @453 TF (2 resident). Same engine, rate ~ residency.
//   gemm12864_sb: A[128][K] staged as before, B 64 rows, LDS 24 KiB ->
//   6 blocks/CU cap; scores grid 2048 (8/CU supply), pu 1024 (4/CU).
//   Extra staging (1.5x per FLOP) is L2-resident per-XCD (batch slices
//   <= 4 MB). qku stays 128x128 sb (measured best).
// Algebra: U = (Wp.Wv).hn + Wp.bv;  out = x + bp + (P.U)/L.
//
// Layouts: hn_t[B][N][C], QKt[B][N][1024]=[Q|K], U[B][C][N],
//          expS bf16 [B][N][N].

#define BATCH 16
#define CCH 512
#define NSP 1024
#define EPSV 1e-5f
#define BK 32      // shorts per half-tile row
#define HT 4096    // shorts per half-tile (128*BK)

typedef short bf16x8 __attribute__((ext_vector_type(8)));
typedef float f32x4 __attribute__((ext_vector_type(4)));

__device__ __forceinline__ unsigned short f2bf(float f) {
    unsigned int u = __float_as_uint(f);
    u += 0x7FFF + ((u >> 16) & 1);  // RNE
    return (unsigned short)(u >> 16);
}

__device__ __forceinline__ void glds16(const void* g, void* l) {
    __builtin_amdgcn_global_load_lds(
        (const __attribute__((address_space(1))) unsigned int*)g,
        (__attribute__((address_space(3))) unsigned int*)l, 16, 0, 0);
}

// Decode 1-D block id -> (x, y, b) with batch pinned to XCD (lin%8).
#define XCD_MAP(GX_LOG2, PER, xv, yv, bv)                 \
    const int lin_ = blockIdx.x;                          \
    const int xcd_ = lin_ & 7;                            \
    int slot_ = lin_ >> 3;                                \
    const int hi_ = (slot_ >= (PER)) ? 1 : 0;             \
    const int bv = xcd_ + 8 * hi_;                        \
    slot_ -= hi_ * (PER);                                 \
    const int xv = slot_ & ((1 << (GX_LOG2)) - 1);        \
    const int yv = slot_ >> (GX_LOG2);

// ------- single-buffer 128x128 NT mainloop (32 KiB), K=64 per iter -------
__device__ __forceinline__ void gemm128_loop(
    const unsigned short* __restrict__ Ag, const unsigned short* __restrict__ Bg,
    int astr, int bstr, int ktot, short* Al, short* Bl, f32x4* acc) {
    const int t = threadIdx.x;
    const int w = t >> 6, lane = t & 63;
    const int wr = (w >> 1) * 64, wc = (w & 1) * 64;
    const int fr = lane & 15;
    const int fsw = (((lane >> 4) ^ (fr & 3)) * 8);  // swizzled read chunk
    const int r0 = t >> 2;        // staging row (4 chunks/row)
    const int kc = (((t & 3) ^ (r0 & 3)) * 8);       // swizzled source chunk
    const unsigned short* Ap0 = Ag + (size_t)r0 * astr + kc;
    const unsigned short* Ap1 = Ag + (size_t)(r0 + 64) * astr + kc;
    const unsigned short* Bp0 = Bg + (size_t)r0 * bstr + kc;
    const unsigned short* Bp1 = Bg + (size_t)(r0 + 64) * bstr + kc;
    short* Alw = Al + w * 512;   // wave-uniform LDS base (lane*16B contiguous)
    short* Blw = Bl + w * 512;
    for (int k0 = 0; k0 < ktot; k0 += 64) {
        glds16(Ap0 + k0, Alw);
        glds16(Ap1 + k0, Alw + 2048);
        glds16(Ap0 + k0 + 32, Alw + HT);
        glds16(Ap1 + k0 + 32, Alw + HT + 2048);
        glds16(Bp0 + k0, Blw);
        glds16(Bp1 + k0, Blw + 2048);
        glds16(Bp0 + k0 + 32, Blw + HT);
        glds16(Bp1 + k0 + 32, Blw + HT + 2048);
        __syncthreads();
#pragma unroll
        for (int h = 0; h < 2; h++) {
            const short* Ab = Al + h * HT;
            const short* Bb = Bl + h * HT;
            bf16x8 af[4], bfr[4];
#pragma unroll
            for (int mi = 0; mi < 4; mi++)
                af[mi] = *(const bf16x8*)(Ab + (wr + mi * 16 + fr) * BK + fsw);
#pragma unroll
            for (int ni = 0; ni < 4; ni++)
                bfr[ni] = *(const bf16x8*)(Bb + (wc + ni * 16 + fr) * BK + fsw);
#pragma unroll
            for (int mi = 0; mi < 4; mi++)
#pragma unroll
                for (int ni = 0; ni < 4; ni++)
                    acc[mi * 4 + ni] = __builtin_amdgcn_mfma_f32_16x16x32_bf16(
                        af[mi], bfr[ni], acc[mi * 4 + ni], 0, 0, 0);
        }
        __syncthreads();
    }
}

// ------- single-buffer 128x64 NT mainloop (24 KiB), K=64 per iter --------
// A = [0,8192) shorts (two K-halves x [128][32]);
// B = [8192,12288) (two K-halves x [64][32]).  Wave grid 2M x 2N.
// acc[8]: acc[mi*2+ni], per-wave output 64x32.
__device__ __forceinline__ void gemm12864_sb(
    const unsigned short* __restrict__ Ag, const unsigned short* __restrict__ Bg,
    int astr, int bstr, int ktot, short* L, f32x4* acc) {
    const int t = threadIdx.x;
    const int w = t >> 6, lane = t & 63;
    const int wr = (w >> 1) * 64, wc = (w & 1) * 32;
    const int fr = lane & 15;
    const int fsw = (((lane >> 4) ^ (fr & 3)) * 8);  // swizzled read chunk
    const int r0 = t >> 2;        // staging row (4 chunks/row)
    const int kc = (((t & 3) ^ (r0 & 3)) * 8);       // swizzled source chunk
    const unsigned short* Ap0 = Ag + (size_t)r0 * astr + kc;
    const unsigned short* Ap1 = Ag + (size_t)(r0 + 64) * astr + kc;
    const unsigned short* Bp0 = Bg + (size_t)r0 * bstr + kc;
    short* Alw = L + w * 512;
    short* Blw = L + 8192 + w * 512;
    for (int k0 = 0; k0 < ktot; k0 += 64) {
        glds16(Ap0 + k0, Alw);
        glds16(Ap1 + k0, Alw + 2048);
        glds16(Ap0 + k0 + 32, Alw + 4096);
        glds16(Ap1 + k0 + 32, Alw + 4096 + 2048);
        glds16(Bp0 + k0, Blw);
        glds16(Bp0 + k0 + 32, Blw + 2048);
        __syncthreads();
#pragma unroll
        for (int h = 0; h < 2; h++) {
            const short* Ab = L + h * 4096;
            const short* Bb = L + 8192 + h * 2048;
            bf16x8 af[4], bfr[2];
#pragma unroll
            for (int mi = 0; mi < 4; mi++)
                af[mi] = *(const bf16x8*)(Ab + (wr + mi * 16 + fr) * 32 + fsw);
#pragma unroll
            for (int ni = 0; ni < 2; ni++)
                bfr[ni] = *(const bf16x8*)(Bb + (wc + ni * 16 + fr) * 32 + fsw);
#pragma unroll
            for (int mi = 0; mi < 4; mi++)
#pragma unroll
                for (int ni = 0; ni < 2; ni++)
                    acc[mi * 2 + ni] = __builtin_amdgcn_mfma_f32_16x16x32_bf16(
                        af[mi], bfr[ni], acc[mi * 2 + ni], 0, 0, 0);
        }
        __syncthreads();
    }
}

#define EPI_SETUP()                                          \
    const int t = threadIdx.x, lane = t & 63, w = t >> 6;    \
    const int wr = (w >> 1) * 64, wc = (w & 1) * 64;         \
    const int fr = lane & 15, rr0 = (lane >> 4) * 4;

#define EPI_SETUP64()                                        \
    const int t = threadIdx.x, lane = t & 63, w = t >> 6;    \
    const int wr = (w >> 1) * 64, wc = (w & 1) * 32;         \
    const int fr = lane & 15, rr0 = (lane >> 4) * 4;

#define ACC_INIT(acc)                                        \
    f32x4 acc[16];                                           \
    _Pragma("unroll") for (int i = 0; i < 16; i++)           \
        acc[i] = (f32x4){0.f, 0.f, 0.f, 0.f};

#define ACC_INIT8(acc)                                       \
    f32x4 acc[8];                                            \
    _Pragma("unroll") for (int i = 0; i < 8; i++)            \
        acc[i] = (f32x4){0.f, 0.f, 0.f, 0.f};

// -- setup grid map --
//  [0,512)      GN stats partial sums (per quarter-group, no atomics)
//  [512,1280)   weight cvt: Q,K rows (na4=131072) then Wp (nb4=65536)
//  [1280,1296)  zero Lsum (64 KiB)
//  [1296,1360)  Wv transpose (64 tiles)
//  [1360,1362)  puv = Wp.bv
__global__ __launch_bounds__(256) void setup_k(
    const float* __restrict__ x, float* __restrict__ sp,
    const float* __restrict__ wa, unsigned short* __restrict__ oa, int na4,
    const float* __restrict__ wb, unsigned short* __restrict__ ob, int nb4,
    float* __restrict__ Lsum, const float* __restrict__ bqv,
    unsigned short* __restrict__ wv_t, float* __restrict__ puv) {
    const int t = threadIdx.x;
    const int bx = blockIdx.x;
    __shared__ float rs[4], rq[4];
    __shared__ __align__(16) unsigned short Tt[64 * 72];
    if (bx < 512) {
        const int bg = bx >> 2, q = bx & 3;
        const float4* xp = (const float4*)(x + (size_t)bg * 65536 + q * 16384);
        float s = 0.f, qq = 0.f;
#pragma unroll
        for (int i = 0; i < 16; i++) {
            float4 v = xp[t + i * 256];
            s += v.x + v.y + v.z + v.w;
            qq += v.x * v.x + v.y * v.y + v.z * v.z + v.w * v.w;
        }
#pragma unroll
        for (int off = 32; off; off >>= 1) {
            s += __shfl_down(s, off);
            qq += __shfl_down(qq, off);
        }
        const int wave = t >> 6, lane = t & 63;
        if (lane == 0) { rs[wave] = s; rq[wave] = qq; }
        __syncthreads();
        if (t == 0) {
            sp[bx * 2] = rs[0] + rs[1] + rs[2] + rs[3];
            sp[bx * 2 + 1] = rq[0] + rq[1] + rq[2] + rq[3];
        }
    } else if (bx < 1280) {
        int i = (bx - 512) * 256 + t;
        const float* src;
        unsigned short* dst;
        int j;
        if (i < na4) { src = wa; dst = oa; j = i; }
        else { j = i - na4; if (j >= nb4) return; src = wb; dst = ob; }
        float4 v = ((const float4*)src)[j];
        ushort4 o;
        o.x = f2bf(v.x); o.y = f2bf(v.y); o.z = f2bf(v.z); o.w = f2bf(v.w);
        ((ushort4*)dst)[j] = o;
    } else if (bx < 1296) {
        int i = (bx - 1280) * 256 + t;  // 16 blocks: zero Lsum (64 KiB)
        ((float4*)Lsum)[i] = (float4){0.f, 0.f, 0.f, 0.f};
    } else if (bx < 1360) {
        // transpose Wv: wv_t[c][v] = w_qkv[1024 + v][c]
        const int r = bx - 1296;
        const float* src = wa + (size_t)2 * 512 * 512;
        const int to = (r >> 3) * 64, tc = (r & 7) * 64;  // v-tile, c-tile
        const int ol = t >> 2, cs = t & 3;
#pragma unroll
        for (int j = 0; j < 4; j++) {
            float4 v = *(const float4*)(src + (size_t)(to + ol) * 512 + tc + cs * 16 + j * 4);
            int c = cs * 16 + j * 4;
            Tt[(c + 0) * 72 + ol] = f2bf(v.x);
            Tt[(c + 1) * 72 + ol] = f2bf(v.y);
            Tt[(c + 2) * 72 + ol] = f2bf(v.z);
            Tt[(c + 3) * 72 + ol] = f2bf(v.w);
        }
        __syncthreads();
        const int cl = t >> 2, os = t & 3;
        unsigned short* d = wv_t + (size_t)(tc + cl) * 512 + to + os * 16;
        const unsigned short* s2 = Tt + cl * 72 + os * 16;
        *(uint4*)d = *(const uint4*)s2;
        *(uint4*)(d + 8) = *(const uint4*)(s2 + 8);
    } else {
        // puv[o] = sum_v Wp[o][v] * bv[v]   (bv = b_qkv[1024..1536))
        const int o = (bx - 1360) * 256 + t;
        const float* wr_ = wb + (size_t)o * 512;
        const float* bv = bqv + 1024;
        float s = 0.f;
        for (int vv = 0; vv < 512; vv += 4) {
            s += wr_[vv] * bv[vv] + wr_[vv + 1] * bv[vv + 1]
               + wr_[vv + 2] * bv[vv + 2] + wr_[vv + 3] * bv[vv + 3];
        }
        puv[o] = s;
    }
}

// ---- gn_tr: lin<16 -> Wpv = Wp.Wv GEMM (sb engine); else GN normalize
//      (folding 4 stats partials) + transpose -> hn_t[B][N][C] bf16.
__global__ __launch_bounds__(256) void gn_tr_k(
    const float* __restrict__ x, const float* __restrict__ gamma,
    const float* __restrict__ beta, const float* __restrict__ sp,
    unsigned short* __restrict__ hn_t,
    const unsigned short* __restrict__ wp_bf, const unsigned short* __restrict__ wv_t,
    unsigned short* __restrict__ wpv_bf) {
    __shared__ __align__(16) short SM[4 * HT];  // 32 KiB (union: GEMM / T-tile)
    const int lin = blockIdx.x;
    const int t = threadIdx.x;
    if (lin < 16) {
        const int ot = (lin >> 2) * 128, ct2 = (lin & 3) * 128;
        ACC_INIT(acc);
        gemm128_loop(wp_bf + (size_t)ot * 512, wv_t + (size_t)ct2 * 512,
                     512, 512, 512, SM, SM + 2 * HT, acc);
        EPI_SETUP();
#pragma unroll
        for (int ni = 0; ni < 4; ni++) {
            int col = ct2 + wc + ni * 16 + fr;
#pragma unroll
            for (int mi = 0; mi < 4; mi++) {
                int row = ot + wr + mi * 16 + rr0;
#pragma unroll
                for (int r = 0; r < 4; r++)
                    wpv_bf[(size_t)(row + r) * 512 + col] = f2bf(acc[mi * 4 + ni][r]);
            }
        }
        return;
    }
    const int l2 = lin - 16;
    const int nt = l2 & 15, ct = (l2 >> 4) & 7, b = l2 >> 7;
    unsigned short* T = (unsigned short*)SM;  // [64][72]
    const int bg = b * 8 + ct;
    float S = 0.f, Q = 0.f;
#pragma unroll
    for (int qq = 0; qq < 4; qq++) {
        S += sp[(bg * 4 + qq) * 2];
        Q += sp[(bg * 4 + qq) * 2 + 1];
    }
    const float inv = 1.f / 65536.f;
    const float mean = S * inv;
    const float rstd = rsqrtf(Q * inv - mean * mean + EPSV);
    const int cl = t >> 2, nc = t & 3;
    const int c = ct * 64 + cl;
    const float ga = gamma[c] * rstd;
    const float be = beta[c] - mean * ga;
    const float4* xp = (const float4*)(x + ((size_t)b * CCH + c) * NSP + nt * 64);
#pragma unroll
    for (int j = 0; j < 4; j++) {
        float4 v = xp[nc * 4 + j];
        int n = nc * 16 + j * 4;
        T[(n + 0) * 72 + cl] = f2bf(v.x * ga + be);
        T[(n + 1) * 72 + cl] = f2bf(v.y * ga + be);
        T[(n + 2) * 72 + cl] = f2bf(v.z * ga + be);
        T[(n + 3) * 72 + cl] = f2bf(v.w * ga + be);
    }
    __syncthreads();
    const int nl = t >> 2, cc = t & 3;
    unsigned short* dst = hn_t + ((size_t)b * NSP + nt * 64 + nl) * CCH + ct * 64 + cc * 16;
    const unsigned short* src = T + nl * 72 + cc * 16;
    *(uint4*)dst = *(const uint4*)src;
    *(uint4*)(dst + 8) = *(const uint4*)(src + 8);
}

// ---------------- QKU: y<8 -> Q|K rows; y>=8 -> U = Wpv.hn (transposed) ----
// grid: 1536 blocks (supply 6/CU -> sb engine, 5 resident)
__global__ __launch_bounds__(256) void gemm_qku_k(
    const unsigned short* __restrict__ hn_t, const unsigned short* __restrict__ wq,
    const float* __restrict__ bq, const unsigned short* __restrict__ wpv_bf,
    const float* __restrict__ puv, unsigned short* __restrict__ QKt,
    unsigned short* __restrict__ Ub) {
    __shared__ __align__(16) short Al[2 * HT], Bl[2 * HT];
    XCD_MAP(3, 96, xb, y, b);
    const int ntc = xb * 128;
    ACC_INIT(acc);
    if (y < 8) {
        const int mt = y * 128;
        gemm128_loop(hn_t + ((size_t)b * NSP + mt) * CCH,
                     wq + (size_t)ntc * CCH, CCH, CCH, CCH, Al, Bl, acc);
        unsigned short* Ob = QKt + (size_t)b * NSP * 1024;
        EPI_SETUP();
#pragma unroll
        for (int ni = 0; ni < 4; ni++) {
            int col = ntc + wc + ni * 16 + fr;
            float bias = bq[col];
#pragma unroll
            for (int mi = 0; mi < 4; mi++) {
                int row = mt + wr + mi * 16 + rr0;
#pragma unroll
                for (int r = 0; r < 4; r++)
                    Ob[(size_t)(row + r) * 1024 + col] = f2bf(acc[mi * 4 + ni][r] + bias);
            }
        }
    } else {
        const int mt = (y - 8) * 128;  // o-tile
        gemm128_loop(wpv_bf + (size_t)mt * 512,
                     hn_t + ((size_t)b * NSP + ntc) * CCH, 512, CCH, 512, Al, Bl, acc);
        unsigned short* Ob = Ub + (size_t)b * CCH * NSP;
        EPI_SETUP();
#pragma unroll
        for (int mi = 0; mi < 4; mi++) {
            int row = mt + wr + mi * 16 + rr0;
#pragma unroll
            for (int r = 0; r < 4; r++) {
                float bias = puv[row + r];
#pragma unroll
                for (int ni = 0; ni < 4; ni++) {
                    int col = ntc + wc + ni * 16 + fr;
                    Ob[(size_t)(row + r) * NSP + col] = f2bf(acc[mi * 4 + ni][r] + bias);
                }
            }
        }
    }
}

// ------- scores+exp: expS[b][n][m]=exp(scale*q.k) bf16; Lsum[b][n] += rowsum
// grid: 2048 blocks, 128x64 tiles: GX=16 (nt), GY=8 (mt), PER=128
__global__ __launch_bounds__(256) void gemm_scores_k(
    const unsigned short* __restrict__ QKt, unsigned short* __restrict__ expS,
    float* __restrict__ Lsum) {
    __shared__ __align__(16) short L[12288];  // 24 KiB
    XCD_MAP(4, 128, xb, yb, b);
    const int nt = xb * 64, mt = yb * 128;
    const unsigned short* base = QKt + (size_t)b * NSP * 1024;
    ACC_INIT8(acc);
    gemm12864_sb(base + (size_t)mt * 1024, base + (size_t)nt * 1024 + 512,
                 1024, 1024, 512, L, acc);
    unsigned short* Ob = expS + (size_t)b * NSP * NSP;
    float* Ls = Lsum + (size_t)b * NSP;
    const float scale = 0.044194173824159216f;  // 512^-0.5
    EPI_SETUP64();
#pragma unroll
    for (int mi = 0; mi < 4; mi++) {
#pragma unroll
        for (int r = 0; r < 4; r++) {
            const int row = mt + wr + mi * 16 + rr0 + r;
            float rs = 0.f;
#pragma unroll
            for (int ni = 0; ni < 2; ni++) {
                int col = nt + wc + ni * 16 + fr;
                float e = __expf(acc[mi * 2 + ni][r] * scale);
                Ob[(size_t)row * NSP + col] = f2bf(e);
                rs += e;
            }
            rs += __shfl_xor(rs, 1);
            rs += __shfl_xor(rs, 2);
            rs += __shfl_xor(rs, 4);
            rs += __shfl_xor(rs, 8);
            if (fr == 0) atomicAdd(&Ls[row], rs);
        }
    }
}

// ------ PU final: out[b][o][n] = x + bp[o] + (U[o][:].expS[n][:]) / L[n] ----
// grid: 1024 blocks, 128x64 tiles: GX=16 (nt), GY=4 (ot), PER=64
__global__ __launch_bounds__(256) void gemm_pu_k(
    const unsigned short* __restrict__ Ub, const unsigned short* __restrict__ expS,
    const float* __restrict__ Lsum, const float* __restrict__ x,
    const float* __restrict__ bp, float* __restrict__ out) {
    __shared__ __align__(16) short L[12288];  // 24 KiB
    XCD_MAP(4, 64, xb, yb, b);
    const int nt = xb * 64, ot = yb * 128;
    ACC_INIT8(acc);
    gemm12864_sb(Ub + ((size_t)b * CCH + ot) * NSP,
                 expS + ((size_t)b * NSP + nt) * NSP, NSP, NSP, NSP, L, acc);
    const float* Ls = Lsum + (size_t)b * NSP;
    const size_t bbase = (size_t)b * CCH * NSP;
    EPI_SETUP64();
#pragma unroll
    for (int ni = 0; ni < 2; ni++) {
        int col = nt + wc + ni * 16 + fr;
        float invl = __builtin_amdgcn_rcpf(Ls[col]);
#pragma unroll
        for (int mi = 0; mi < 4; mi++) {
            int row = ot + wr + mi * 16 + rr0;
#pragma unroll
            for (int r = 0; r < 4; r++) {
                size_t idx = bbase + (size_t)(row + r) * NSP + col;
                out[idx] = x[idx] + bp[row + r] + acc[mi * 2 + ni][r] * invl;
            }
        }
    }
}

extern "C" void kernel_launch(void* const* d_in, const int* in_sizes, int n_in,
                              void* d_out, int out_size, void* d_ws, size_t ws_size,
                              hipStream_t stream) {
    const float* x = (const float*)d_in[0];
    const float* gamma = (const float*)d_in[1];
    const float* beta = (const float*)d_in[2];
    const float* w_qkv = (const float*)d_in[3];
    const float* b_qkv = (const float*)d_in[4];
    const float* w_proj = (const float*)d_in[5];
    const float* b_proj = (const float*)d_in[6];
    float* out = (float*)d_out;

    char* ws = (char*)d_ws;
    const size_t MB = 1048576;
    const size_t KB = 1024;
    unsigned short* wqkv_bf = (unsigned short*)ws;               // 1 MiB (Q,K rows)
    unsigned short* wproj_bf = (unsigned short*)(ws + 1572864);  // 0.5 MiB
    float* sp = (float*)(ws + 2 * MB);                           // 4 KiB partials
    float* Lsum = (float*)(ws + 2 * MB + 64 * KB);               // 64 KiB
    float* puv = (float*)(ws + 2 * MB + 128 * KB);               // 2 KiB
    unsigned short* wv_t = (unsigned short*)(ws + 2 * MB + 256 * KB);  // 512 KiB
    unsigned short* wpv_bf = (unsigned short*)(ws + 3 * MB);     // 512 KiB
    unsigned short* hn_t = (unsigned short*)(ws + 4 * MB);       // 16.8 MiB
    unsigned short* QKt = (unsigned short*)(ws + 24 * MB);       // 33.5 MiB
    unsigned short* Ub = (unsigned short*)(ws + 60 * MB);        // 16.8 MiB
    unsigned short* expS = (unsigned short*)(ws + 80 * MB);      // 33.5 MiB

    setup_k<<<1362, 256, 0, stream>>>(x, sp, w_qkv, wqkv_bf, 131072,
                                      w_proj, wproj_bf, 65536, Lsum, b_qkv,
                                      wv_t, puv);
    gn_tr_k<<<2064, 256, 0, stream>>>(x, gamma, beta, sp, hn_t,
                                      wproj_bf, wv_t, wpv_bf);
    gemm_qku_k<<<1536, 256, 0, stream>>>(hn_t, wqkv_bf, b_qkv, wpv_bf, puv,
                                         QKt, Ub);
    gemm_scores_k<<<2048, 256, 0, stream>>>(QKt, expS, Lsum);
    gemm_pu_k<<<1024, 256, 0, stream>>>(Ub, expS, Lsum, x, b_proj, out);
}

// Round 11
// 204.289 us; speedup vs baseline: 1.1063x; 1.1063x over previous
//
#include <hip/hip_runtime.h>

// Attention block: B=16, C=512, H=W=32 (N=1024), GROUPS=8, EPS=1e-5
// All GEMMs NT-form bf16 MFMA, global_load_lds width-16 staging.
//
// R17 = R11 verbatim (best measured: 204.56 us). Rationale:
//  - R10->R11 is the session's only clean same-structure A/B: moving
//    qku/scores/pu to the counted-vmcnt 64 KiB dbuf engine = -16.4 us.
//  - Every later deviation (Wqk algebra R12, K=32 phases R13, 64-wide
//    tiles R14/R16, per-dispatch engine mixing R15) measured neutral or
//    worse on totals; scores proven invariant (~41.5 us) to residency
//    (R16: occupancy 16->37% with dur unchanged).
//  - Cross-session total noise ~+-5 us dominates below the 10 us scale;
//    lock in the best-measured configuration.
// Engine: per half-iter {STAGE(other buf) -> vmcnt(8) -> raw s_barrier ->
// 32 MFMA -> raw s_barrier}; NEVER vmcnt(0) in-loop.
// Algebra: U = (Wp.Wv).hn + Wp.bv;  out = x + bp + (P.U)/L.
//
// Layouts: hn_t[B][N][C], QKt[B][N][1024]=[Q|K], U[B][C][N],
//          expS bf16 [B][N][N].

#define BATCH 16
#define CCH 512
#define NSP 1024
#define EPSV 1e-5f
#define BK 32      // shorts per half-tile row
#define HT 4096    // shorts per half-tile (128*BK)

typedef short bf16x8 __attribute__((ext_vector_type(8)));
typedef float f32x4 __attribute__((ext_vector_type(4)));

__device__ __forceinline__ unsigned short f2bf(float f) {
    unsigned int u = __float_as_uint(f);
    u += 0x7FFF + ((u >> 16) & 1);  // RNE
    return (unsigned short)(u >> 16);
}

__device__ __forceinline__ void glds16(const void* g, void* l) {
    __builtin_amdgcn_global_load_lds(
        (const __attribute__((address_space(1))) unsigned int*)g,
        (__attribute__((address_space(3))) unsigned int*)l, 16, 0, 0);
}

#define MEMF asm volatile("" ::: "memory")
#define VMW(n) asm volatile("s_waitcnt vmcnt(" #n ")" ::: "memory")

// Decode 1-D block id -> (x, y, b) with batch pinned to XCD (lin%8).
#define XCD_MAP(GX_LOG2, PER, xv, yv, bv)                 \
    const int lin_ = blockIdx.x;                          \
    const int xcd_ = lin_ & 7;                            \
    int slot_ = lin_ >> 3;                                \
    const int hi_ = (slot_ >= (PER)) ? 1 : 0;             \
    const int bv = xcd_ + 8 * hi_;                        \
    slot_ -= hi_ * (PER);                                 \
    const int xv = slot_ & ((1 << (GX_LOG2)) - 1);        \
    const int yv = slot_ >> (GX_LOG2);

// ------------- double-buffered 128x128 NT mainloop, counted vmcnt -------
// L = 8*HT shorts (64 KiB): buf b at b*4HT = [A 2HT | B 2HT].
// ktot must be a multiple of 128.
__device__ __forceinline__ void gemm128_dbuf(
    const unsigned short* __restrict__ Ag, const unsigned short* __restrict__ Bg,
    int astr, int bstr, int ktot, short* L, f32x4* acc) {
    const int t = threadIdx.x;
    const int w = t >> 6, lane = t & 63;
    const int wr = (w >> 1) * 64, wc = (w & 1) * 64;
    const int fr = lane & 15;
    const int fsw = (((lane >> 4) ^ (fr & 3)) * 8);  // swizzled read chunk
    const int r0 = t >> 2;        // staging row (4 chunks/row)
    const int kc = (((t & 3) ^ (r0 & 3)) * 8);       // swizzled source chunk
    const unsigned short* Ap0 = Ag + (size_t)r0 * astr + kc;
    const unsigned short* Ap1 = Ag + (size_t)(r0 + 64) * astr + kc;
    const unsigned short* Bp0 = Bg + (size_t)r0 * bstr + kc;
    const unsigned short* Bp1 = Bg + (size_t)(r0 + 64) * bstr + kc;
    short* lw = L + w * 512;     // wave-uniform LDS base (lane*16B contiguous)

#define STG(bf, kk) do {                                  \
    short* aw_ = lw + (bf) * (4 * HT);                    \
    short* bw_ = aw_ + 2 * HT;                            \
    glds16(Ap0 + (kk), aw_);                              \
    glds16(Ap1 + (kk), aw_ + 2048);                       \
    glds16(Ap0 + (kk) + 32, aw_ + HT);                    \
    glds16(Ap1 + (kk) + 32, aw_ + HT + 2048);             \
    glds16(Bp0 + (kk), bw_);                              \
    glds16(Bp1 + (kk), bw_ + 2048);                       \
    glds16(Bp0 + (kk) + 32, bw_ + HT);                    \
    glds16(Bp1 + (kk) + 32, bw_ + HT + 2048);             \
  } while (0)

#define CMP(bf) do {                                                        \
    _Pragma("unroll")                                                       \
    for (int h = 0; h < 2; h++) {                                           \
        const short* Ab_ = L + (bf) * (4 * HT) + h * HT;                    \
        const short* Bb_ = Ab_ + 2 * HT;                                    \
        bf16x8 af[4], bfr[4];                                               \
        _Pragma("unroll")                                                   \
        for (int mi = 0; mi < 4; mi++)                                      \
            af[mi] = *(const bf16x8*)(Ab_ + (wr + mi * 16 + fr) * BK + fsw);\
        _Pragma("unroll")                                                   \
        for (int ni = 0; ni < 4; ni++)                                      \
            bfr[ni] = *(const bf16x8*)(Bb_ + (wc + ni * 16 + fr) * BK + fsw);\
        _Pragma("unroll")                                                   \
        for (int mi = 0; mi < 4; mi++)                                      \
            _Pragma("unroll")                                               \
            for (int ni = 0; ni < 4; ni++)                                  \
                acc[mi * 4 + ni] = __builtin_amdgcn_mfma_f32_16x16x32_bf16( \
                    af[mi], bfr[ni], acc[mi * 4 + ni], 0, 0, 0);            \
    } } while (0)

    STG(0, 0);
    for (int k0 = 0; k0 < ktot; k0 += 128) {
        STG(1, k0 + 64);               // prefetch tile k+64 into buf1
        VMW(8);                        // buf0's 8 loads done; 8 stay in flight
        MEMF; __builtin_amdgcn_s_barrier();
        CMP(0);
        MEMF; __builtin_amdgcn_s_barrier();
        const int kb = (k0 + 128 < ktot) ? k0 + 128 : 0;  // tail: garbage
        STG(0, kb);                    // prefetch tile k+128 into buf0
        VMW(8);                        // buf1's 8 loads done
        MEMF; __builtin_amdgcn_s_barrier();
        CMP(1);
        MEMF; __builtin_amdgcn_s_barrier();
    }
    VMW(0);                            // drain tail garbage before epilogue
#undef STG
#undef CMP
}

// ---------------- single-buffer engine (gn_tr's 16 Wpv blocks only) -------
__device__ __forceinline__ void gemm128_sb(
    const unsigned short* __restrict__ Ag, const unsigned short* __restrict__ Bg,
    int astr, int bstr, int ktot, short* Al, short* Bl, f32x4* acc) {
    const int t = threadIdx.x;
    const int w = t >> 6, lane = t & 63;
    const int wr = (w >> 1) * 64, wc = (w & 1) * 64;
    const int fr = lane & 15;
    const int fsw = (((lane >> 4) ^ (fr & 3)) * 8);
    const int r0 = t >> 2;
    const int kc = (((t & 3) ^ (r0 & 3)) * 8);
    const unsigned short* Ap0 = Ag + (size_t)r0 * astr + kc;
    const unsigned short* Ap1 = Ag + (size_t)(r0 + 64) * astr + kc;
    const unsigned short* Bp0 = Bg + (size_t)r0 * bstr + kc;
    const unsigned short* Bp1 = Bg + (size_t)(r0 + 64) * bstr + kc;
    short* Alw = Al + w * 512;
    short* Blw = Bl + w * 512;
    for (int k0 = 0; k0 < ktot; k0 += 64) {
        glds16(Ap0 + k0, Alw);
        glds16(Ap1 + k0, Alw + 2048);
        glds16(Ap0 + k0 + 32, Alw + HT);
        glds16(Ap1 + k0 + 32, Alw + HT + 2048);
        glds16(Bp0 + k0, Blw);
        glds16(Bp1 + k0, Blw + 2048);
        glds16(Bp0 + k0 + 32, Blw + HT);
        glds16(Bp1 + k0 + 32, Blw + HT + 2048);
        __syncthreads();
#pragma unroll
        for (int h = 0; h < 2; h++) {
            const short* Ab = Al + h * HT;
            const short* Bb = Bl + h * HT;
            bf16x8 af[4], bfr[4];
#pragma unroll
            for (int mi = 0; mi < 4; mi++)
                af[mi] = *(const bf16x8*)(Ab + (wr + mi * 16 + fr) * BK + fsw);
#pragma unroll
            for (int ni = 0; ni < 4; ni++)
                bfr[ni] = *(const bf16x8*)(Bb + (wc + ni * 16 + fr) * BK + fsw);
#pragma unroll
            for (int mi = 0; mi < 4; mi++)
#pragma unroll
                for (int ni = 0; ni < 4; ni++)
                    acc[mi * 4 + ni] = __builtin_amdgcn_mfma_f32_16x16x32_bf16(
                        af[mi], bfr[ni], acc[mi * 4 + ni], 0, 0, 0);
        }
        __syncthreads();
    }
}

#define EPI_SETUP()                                          \
    const int t = threadIdx.x, lane = t & 63, w = t >> 6;    \
    const int wr = (w >> 1) * 64, wc = (w & 1) * 64;         \
    const int fr = lane & 15, rr0 = (lane >> 4) * 4;

#define ACC_INIT(acc)                                        \
    f32x4 acc[16];                                           \
    _Pragma("unroll") for (int i = 0; i < 16; i++)           \
        acc[i] = (f32x4){0.f, 0.f, 0.f, 0.f};

// -- setup: GN stats (0..127) + weight cvt Q,K,Wp (128..895) + zero Lsum
//    (896..911) + Wv transpose (912..975) + pu_vec = Wp.bv (976..977) --
__global__ __launch_bounds__(256) void setup_k(
    const float* __restrict__ x, float* __restrict__ stats,
    const float* __restrict__ wa, unsigned short* __restrict__ oa, int na4,
    const float* __restrict__ wb, unsigned short* __restrict__ ob, int nb4,
    float* __restrict__ Lsum, const float* __restrict__ bqv,
    unsigned short* __restrict__ wv_t, float* __restrict__ puv) {
    const int t = threadIdx.x;
    const int bx = blockIdx.x;
    __shared__ float rs[4], rq[4];
    __shared__ __align__(16) unsigned short Tt[64 * 72];
    if (bx < 128) {
        const int bg = bx;
        const float4* xp = (const float4*)(x + (size_t)bg * 65536);
        float s = 0.f, q = 0.f;
#pragma unroll
        for (int i = 0; i < 64; i++) {
            float4 v = xp[t + i * 256];
            s += v.x + v.y + v.z + v.w;
            q += v.x * v.x + v.y * v.y + v.z * v.z + v.w * v.w;
        }
#pragma unroll
        for (int off = 32; off; off >>= 1) {
            s += __shfl_down(s, off);
            q += __shfl_down(q, off);
        }
        const int wave = t >> 6, lane = t & 63;
        if (lane == 0) { rs[wave] = s; rq[wave] = q; }
        __syncthreads();
        if (t == 0) {
            float S = rs[0] + rs[1] + rs[2] + rs[3];
            float Q = rq[0] + rq[1] + rq[2] + rq[3];
            const float inv = 1.f / 65536.f;
            float mean = S * inv;
            float var = Q * inv - mean * mean;
            stats[bg * 2] = mean;
            stats[bg * 2 + 1] = rsqrtf(var + EPSV);
        }
    } else if (bx < 896) {
        int i = (bx - 128) * 256 + t;
        const float* src;
        unsigned short* dst;
        int j;
        if (i < na4) { src = wa; dst = oa; j = i; }
        else { j = i - na4; if (j >= nb4) return; src = wb; dst = ob; }
        float4 v = ((const float4*)src)[j];
        ushort4 o;
        o.x = f2bf(v.x); o.y = f2bf(v.y); o.z = f2bf(v.z); o.w = f2bf(v.w);
        ((ushort4*)dst)[j] = o;
    } else if (bx < 912) {
        int i = (bx - 896) * 256 + t;  // 16 blocks: zero Lsum (64 KiB)
        ((float4*)Lsum)[i] = (float4){0.f, 0.f, 0.f, 0.f};
    } else if (bx < 976) {
        // transpose Wv: wv_t[c][v] = w_qkv[1024 + v][c]
        const int r = bx - 912;
        const float* src = wa + (size_t)2 * 512 * 512;
        const int to = (r >> 3) * 64, tc = (r & 7) * 64;  // v-tile, c-tile
        const int ol = t >> 2, cs = t & 3;
#pragma unroll
        for (int j = 0; j < 4; j++) {
            float4 v = *(const float4*)(src + (size_t)(to + ol) * 512 + tc + cs * 16 + j * 4);
            int c = cs * 16 + j * 4;
            Tt[(c + 0) * 72 + ol] = f2bf(v.x);
            Tt[(c + 1) * 72 + ol] = f2bf(v.y);
            Tt[(c + 2) * 72 + ol] = f2bf(v.z);
            Tt[(c + 3) * 72 + ol] = f2bf(v.w);
        }
        __syncthreads();
        const int cl = t >> 2, os = t & 3;
        unsigned short* d = wv_t + (size_t)(tc + cl) * 512 + to + os * 16;
        const unsigned short* s2 = Tt + cl * 72 + os * 16;
        *(uint4*)d = *(const uint4*)s2;
        *(uint4*)(d + 8) = *(const uint4*)(s2 + 8);
    } else {
        // puv[o] = sum_v Wp[o][v] * bv[v]   (bv = b_qkv[1024..1536))
        const int o = (bx - 976) * 256 + t;
        const float* wr_ = wb + (size_t)o * 512;
        const float* bv = bqv + 1024;
        float s = 0.f;
        for (int vv = 0; vv < 512; vv += 4) {
            s += wr_[vv] * bv[vv] + wr_[vv + 1] * bv[vv + 1]
               + wr_[vv + 2] * bv[vv + 2] + wr_[vv + 3] * bv[vv + 3];
        }
        puv[o] = s;
    }
}

// ---- gn_tr + Wpv: lin<16 -> Wpv = Wp x Wv^T GEMM (16 sb-engine blocks);
//      else GN normalize + transpose -> hn_t[B][N][C] bf16.
__global__ __launch_bounds__(256) void gn_tr_k(
    const float* __restrict__ x, const float* __restrict__ gamma,
    const float* __restrict__ beta, const float* __restrict__ stats,
    unsigned short* __restrict__ hn_t,
    const unsigned short* __restrict__ wp_bf, const unsigned short* __restrict__ wv_t,
    unsigned short* __restrict__ wpv_bf) {
    __shared__ __align__(16) short SM[4 * HT];  // 32 KiB (union: GEMM / T-tile)
    const int lin = blockIdx.x;
    const int t = threadIdx.x;
    if (lin < 16) {
        // Wpv[o][c] = sum_v Wp[o][v] * Wv[v][c];  A=Wp[o][v], B=wv_t[c][v]
        const int ot = (lin >> 2) * 128, ct2 = (lin & 3) * 128;
        ACC_INIT(acc);
        gemm128_sb(wp_bf + (size_t)ot * 512, wv_t + (size_t)ct2 * 512,
                   512, 512, 512, SM, SM + 2 * HT, acc);
        EPI_SETUP();
#pragma unroll
        for (int ni = 0; ni < 4; ni++) {
            int col = ct2 + wc + ni * 16 + fr;
#pragma unroll
            for (int mi = 0; mi < 4; mi++) {
                int row = ot + wr + mi * 16 + rr0;
#pragma unroll
                for (int r = 0; r < 4; r++)
                    wpv_bf[(size_t)(row + r) * 512 + col] = f2bf(acc[mi * 4 + ni][r]);
            }
        }
        return;
    }
    const int l2 = lin - 16;
    const int nt = l2 & 15, ct = (l2 >> 4) & 7, b = l2 >> 7;
    unsigned short* T = (unsigned short*)SM;  // [64][72]
    const float mean = stats[(b * 8 + ct) * 2];
    const float rstd = stats[(b * 8 + ct) * 2 + 1];
    const int cl = t >> 2, nc = t & 3;
    const int c = ct * 64 + cl;
    const float ga = gamma[c] * rstd;
    const float be = beta[c] - mean * ga;
    const float4* xp = (const float4*)(x + ((size_t)b * CCH + c) * NSP + nt * 64);
#pragma unroll
    for (int j = 0; j < 4; j++) {
        float4 v = xp[nc * 4 + j];
        int n = nc * 16 + j * 4;
        T[(n + 0) * 72 + cl] = f2bf(v.x * ga + be);
        T[(n + 1) * 72 + cl] = f2bf(v.y * ga + be);
        T[(n + 2) * 72 + cl] = f2bf(v.z * ga + be);
        T[(n + 3) * 72 + cl] = f2bf(v.w * ga + be);
    }
    __syncthreads();
    const int nl = t >> 2, cc = t & 3;
    unsigned short* dst = hn_t + ((size_t)b * NSP + nt * 64 + nl) * CCH + ct * 64 + cc * 16;
    const unsigned short* src = T + nl * 72 + cc * 16;
    *(uint4*)dst = *(const uint4*)src;
    *(uint4*)(dst + 8) = *(const uint4*)(src + 8);
}

// ---------------- QKU: y<8 -> Q|K rows; y>=8 -> U = Wpv.hn (transposed) ----
// grid: 1536 blocks, GX=8 (ntc), GY=12 (y), PER=96
__global__ __launch_bounds__(256) void gemm_qku_k(
    const unsigned short* __restrict__ hn_t, const unsigned short* __restrict__ wq,
    const float* __restrict__ bq, const unsigned short* __restrict__ wpv_bf,
    const float* __restrict__ puv, unsigned short* __restrict__ QKt,
    unsigned short* __restrict__ Ub) {
    __shared__ __align__(16) short L[8 * HT];  // 64 KiB dbuf
    XCD_MAP(3, 96, xb, y, b);
    const int ntc = xb * 128;
    ACC_INIT(acc);
    if (y < 8) {
        const int mt = y * 128;
        gemm128_dbuf(hn_t + ((size_t)b * NSP + mt) * CCH,
                     wq + (size_t)ntc * CCH, CCH, CCH, CCH, L, acc);
        unsigned short* Ob = QKt + (size_t)b * NSP * 1024;
        EPI_SETUP();
#pragma unroll
        for (int ni = 0; ni < 4; ni++) {
            int col = ntc + wc + ni * 16 + fr;
            float bias = bq[col];
#pragma unroll
            for (int mi = 0; mi < 4; mi++) {
                int row = mt + wr + mi * 16 + rr0;
#pragma unroll
                for (int r = 0; r < 4; r++)
                    Ob[(size_t)(row + r) * 1024 + col] = f2bf(acc[mi * 4 + ni][r] + bias);
            }
        }
    } else {
        const int mt = (y - 8) * 128;  // o-tile
        gemm128_dbuf(wpv_bf + (size_t)mt * 512,
                     hn_t + ((size_t)b * NSP + ntc) * CCH, 512, CCH, 512, L, acc);
        unsigned short* Ob = Ub + (size_t)b * CCH * NSP;
        EPI_SETUP();
#pragma unroll
        for (int mi = 0; mi < 4; mi++) {
            int row = mt + wr + mi * 16 + rr0;
#pragma unroll
            for (int r = 0; r < 4; r++) {
                float bias = puv[row + r];
#pragma unroll
                for (int ni = 0; ni < 4; ni++) {
                    int col = ntc + wc + ni * 16 + fr;
                    Ob[(size_t)(row + r) * NSP + col] = f2bf(acc[mi * 4 + ni][r] + bias);
                }
            }
        }
    }
}

// ------- scores+exp: expS[b][n][m]=exp(scale*q.k) bf16; Lsum[b][n] += rowsum ----
// grid: 1024 blocks, GX=8 (nt), GY=8 (mt), PER=64
__global__ __launch_bounds__(256) void gemm_scores_k(
    const unsigned short* __restrict__ QKt, unsigned short* __restrict__ expS,
    float* __restrict__ Lsum) {
    __shared__ __align__(16) short L[8 * HT];  // 64 KiB dbuf
    XCD_MAP(3, 64, xb, yb, b);
    const int nt = xb * 128, mt = yb * 128;
    const unsigned short* base = QKt + (size_t)b * NSP * 1024;
    ACC_INIT(acc);
    gemm128_dbuf(base + (size_t)mt * 1024, base + (size_t)nt * 1024 + 512,
                 1024, 1024, 512, L, acc);
    unsigned short* Ob = expS + (size_t)b * NSP * NSP;
    float* Ls = Lsum + (size_t)b * NSP;
    const float scale = 0.044194173824159216f;  // 512^-0.5
    EPI_SETUP();
#pragma unroll
    for (int mi = 0; mi < 4; mi++) {
#pragma unroll
        for (int r = 0; r < 4; r++) {
            const int row = mt + wr + mi * 16 + rr0 + r;
            float rs = 0.f;
#pragma unroll
            for (int ni = 0; ni < 4; ni++) {
                int col = nt + wc + ni * 16 + fr;
                float e = __expf(acc[mi * 4 + ni][r] * scale);
                Ob[(size_t)row * NSP + col] = f2bf(e);
                rs += e;
            }
            rs += __shfl_xor(rs, 1);
            rs += __shfl_xor(rs, 2);
            rs += __shfl_xor(rs, 4);
            rs += __shfl_xor(rs, 8);
            if (fr == 0) atomicAdd(&Ls[row], rs);
        }
    }
}

// ------ PU final: out[b][o][n] = x + bp[o] + (U[o][:].expS[n][:]) / L[n] ----
// grid: 512 blocks, GX=8 (nt), GY=4 (ot), PER=32
__global__ __launch_bounds__(256) void gemm_pu_k(
    const unsigned short* __restrict__ Ub, const unsigned short* __restrict__ expS,
    const float* __restrict__ Lsum, const float* __restrict__ x,
    const float* __restrict__ bp, float* __restrict__ out) {
    __shared__ __align__(16) short L[8 * HT];  // 64 KiB dbuf
    XCD_MAP(3, 32, xb, yb, b);
    const int nt = xb * 128, ot = yb * 128;
    ACC_INIT(acc);
    gemm128_dbuf(Ub + ((size_t)b * CCH + ot) * NSP,
                 expS + ((size_t)b * NSP + nt) * NSP, NSP, NSP, NSP, L, acc);
    const float* Ls = Lsum + (size_t)b * NSP;
    const size_t bbase = (size_t)b * CCH * NSP;
    EPI_SETUP();
#pragma unroll
    for (int ni = 0; ni < 4; ni++) {
        int col = nt + wc + ni * 16 + fr;
        float invl = __builtin_amdgcn_rcpf(Ls[col]);
#pragma unroll
        for (int mi = 0; mi < 4; mi++) {
            int row = ot + wr + mi * 16 + rr0;
#pragma unroll
            for (int r = 0; r < 4; r++) {
                size_t idx = bbase + (size_t)(row + r) * NSP + col;
                out[idx] = x[idx] + bp[row + r] + acc[mi * 4 + ni][r] * invl;
            }
        }
    }
}

extern "C" void kernel_launch(void* const* d_in, const int* in_sizes, int n_in,
                              void* d_out, int out_size, void* d_ws, size_t ws_size,
                              hipStream_t stream) {
    const float* x = (const float*)d_in[0];
    const float* gamma = (const float*)d_in[1];
    const float* beta = (const float*)d_in[2];
    const float* w_qkv = (const float*)d_in[3];
    const float* b_qkv = (const float*)d_in[4];
    const float* w_proj = (const float*)d_in[5];
    const float* b_proj = (const float*)d_in[6];
    float* out = (float*)d_out;

    char* ws = (char*)d_ws;
    const size_t MB = 1048576;
    const size_t KB = 1024;
    unsigned short* wqkv_bf = (unsigned short*)ws;               // 1 MiB (Q,K rows)
    unsigned short* wproj_bf = (unsigned short*)(ws + 1572864);  // 0.5 MiB
    float* stats = (float*)(ws + 2 * MB);                        // 1 KiB
    float* Lsum = (float*)(ws + 2 * MB + 64 * KB);               // 64 KiB
    float* puv = (float*)(ws + 2 * MB + 128 * KB);               // 2 KiB
    unsigned short* wv_t = (unsigned short*)(ws + 2 * MB + 256 * KB);  // 512 KiB
    unsigned short* wpv_bf = (unsigned short*)(ws + 3 * MB);     // 512 KiB
    unsigned short* hn_t = (unsigned short*)(ws + 4 * MB);       // 16.8 MiB
    unsigned short* QKt = (unsigned short*)(ws + 24 * MB);       // 33.5 MiB
    unsigned short* Ub = (unsigned short*)(ws + 60 * MB);        // 16.8 MiB
    unsigned short* expS = (unsigned short*)(ws + 80 * MB);      // 33.5 MiB

    setup_k<<<978, 256, 0, stream>>>(x, stats, w_qkv, wqkv_bf, 131072,
                                     w_proj, wproj_bf, 65536, Lsum, b_qkv,
                                     wv_t, puv);
    gn_tr_k<<<2064, 256, 0, stream>>>(x, gamma, beta, stats, hn_t,
                                      wproj_bf, wv_t, wpv_bf);
    gemm_qku_k<<<1536, 256, 0, stream>>>(hn_t, wqkv_bf, b_qkv, wpv_bf, puv,
                                         QKt, Ub);
    gemm_scores_k<<<1024, 256, 0, stream>>>(QKt, expS, Lsum);
    gemm_pu_k<<<512, 256, 0, stream>>>(Ub, expS, Lsum, x, b_proj, out);
}